// Round 4
// baseline (99.282 us; speedup 1.0000x reference)
//
#include <hip/hip_runtime.h>

#define EPS 1e-8f
#define NBLOCKS 2048
#define NTHREADS 256
#define COUNTER_OFF 16384  // byte offset of counter in d_ws (partials: 2048*8B)

__global__ __launch_bounds__(NTHREADS) void cl_fused(
    const float4* __restrict__ o4p,
    const float4* __restrict__ t4p,
    const float2* __restrict__ w2p,
    float2* __restrict__ partials,
    unsigned int* __restrict__ counter,
    float* __restrict__ out,
    int M,      // number of float4 groups = N/2
    float invN)
{
    int tid = blockIdx.x * NTHREADS + threadIdx.x;
    int stride = gridDim.x * NTHREADS;

    float s0 = 0.0f, s1 = 0.0f;

    for (int j = tid; j < M; j += stride) {
        float4 o4 = o4p[j];
        float4 t4 = t4p[j];
        float2 w2 = w2p[j];

        float lA0m = __logf((1.0f - o4.x) + EPS);
        float lA0  = __logf(o4.x + EPS);
        float lA1m = __logf((1.0f - o4.y) + EPS);
        float lA1  = __logf(o4.y + EPS);
        s0 += (t4.x * lA0m + t4.y * lA0) * w2.x;
        s1 += (t4.x * lA1m + t4.y * lA1) * w2.x;

        float lB0m = __logf((1.0f - o4.z) + EPS);
        float lB0  = __logf(o4.z + EPS);
        float lB1m = __logf((1.0f - o4.w) + EPS);
        float lB1  = __logf(o4.w + EPS);
        s0 += (t4.z * lB0m + t4.w * lB0) * w2.y;
        s1 += (t4.z * lB1m + t4.w * lB1) * w2.y;
    }

    // wave (64-lane) reduction
    #pragma unroll
    for (int off = 32; off > 0; off >>= 1) {
        s0 += __shfl_down(s0, off, 64);
        s1 += __shfl_down(s1, off, 64);
    }

    __shared__ float sm[(NTHREADS / 64) * 2];
    __shared__ int is_last;
    int wave = threadIdx.x >> 6;
    int lane = threadIdx.x & 63;
    if (lane == 0) { sm[wave * 2 + 0] = s0; sm[wave * 2 + 1] = s1; }
    __syncthreads();

    if (threadIdx.x == 0) {
        float b0 = 0.0f, b1 = 0.0f;
        #pragma unroll
        for (int wv = 0; wv < NTHREADS / 64; ++wv) {
            b0 += sm[wv * 2 + 0];
            b1 += sm[wv * 2 + 1];
        }
        partials[blockIdx.x] = make_float2(b0, b1);
        __threadfence();                       // release: publish partial
        unsigned int old = atomicAdd(counter, 1u);
        is_last = (old == gridDim.x - 1) ? 1 : 0;
    }
    __syncthreads();

    if (is_last) {
        __threadfence();                       // acquire: invalidate stale L2
        double d0 = 0.0, d1 = 0.0;
        for (int j = threadIdx.x; j < (int)gridDim.x; j += NTHREADS) {
            float2 p = partials[j];            // fixed order -> deterministic
            d0 += (double)p.x;
            d1 += (double)p.y;
        }
        #pragma unroll
        for (int off = 32; off > 0; off >>= 1) {
            d0 += __shfl_down(d0, off, 64);
            d1 += __shfl_down(d1, off, 64);
        }
        __shared__ double dm[(NTHREADS / 64) * 2];
        if (lane == 0) { dm[wave * 2 + 0] = d0; dm[wave * 2 + 1] = d1; }
        __syncthreads();
        if (threadIdx.x == 0) {
            double f0 = 0.0, f1 = 0.0;
            #pragma unroll
            for (int wv = 0; wv < NTHREADS / 64; ++wv) {
                f0 += dm[wv * 2 + 0];
                f1 += dm[wv * 2 + 1];
            }
            out[0] = (float)(-f0 * (double)invN);
            out[1] = (float)(-f1 * (double)invN);
        }
    }
}

extern "C" void kernel_launch(void* const* d_in, const int* in_sizes, int n_in,
                              void* d_out, int out_size, void* d_ws, size_t ws_size,
                              hipStream_t stream) {
    const float* outputs = (const float*)d_in[0];  // (B,T,2)
    const float* targets = (const float*)d_in[1];  // (B,T,2)
    const float* weights = (const float*)d_in[2];  // (B,T)

    int N = in_sizes[2];        // B*T
    int M = N / 2;              // float4 groups

    float2* partials = (float2*)d_ws;
    unsigned int* counter = (unsigned int*)((char*)d_ws + COUNTER_OFF);
    float* out = (float*)d_out;

    int nblocks = (M + NTHREADS - 1) / NTHREADS;
    if (nblocks > NBLOCKS) nblocks = NBLOCKS;

    // zero the completion counter (graph-capturable async memset node)
    hipMemsetAsync(counter, 0, sizeof(unsigned int), stream);

    cl_fused<<<nblocks, NTHREADS, 0, stream>>>(
        (const float4*)outputs, (const float4*)targets, (const float2*)weights,
        partials, counter, out, M, 1.0f / (float)N);
}

// Round 5
// 36.031 us; speedup vs baseline: 2.7555x; 2.7555x over previous
//
#include <hip/hip_runtime.h>

#define EPS 1e-8f
#define NBLOCKS 2048
#define NTHREADS 256

// Stage 1: grid-stride partial reduction (R1-proven structure).
// float4 group j covers (b,t) items 2j, 2j+1.
__global__ __launch_bounds__(NTHREADS) void cl_partial(
    const float4* __restrict__ o4p,
    const float4* __restrict__ t4p,
    const float2* __restrict__ w2p,
    float2* __restrict__ partials,
    int M)  // number of float4 groups = N/2
{
    int tid = blockIdx.x * NTHREADS + threadIdx.x;
    int stride = gridDim.x * NTHREADS;

    float s0 = 0.0f, s1 = 0.0f;

    for (int j = tid; j < M; j += stride) {
        float4 o4 = o4p[j];
        float4 t4 = t4p[j];
        float2 w2 = w2p[j];

        float lA0m = __logf((1.0f - o4.x) + EPS);
        float lA0  = __logf(o4.x + EPS);
        float lA1m = __logf((1.0f - o4.y) + EPS);
        float lA1  = __logf(o4.y + EPS);
        s0 += (t4.x * lA0m + t4.y * lA0) * w2.x;
        s1 += (t4.x * lA1m + t4.y * lA1) * w2.x;

        float lB0m = __logf((1.0f - o4.z) + EPS);
        float lB0  = __logf(o4.z + EPS);
        float lB1m = __logf((1.0f - o4.w) + EPS);
        float lB1  = __logf(o4.w + EPS);
        s0 += (t4.z * lB0m + t4.w * lB0) * w2.y;
        s1 += (t4.z * lB1m + t4.w * lB1) * w2.y;
    }

    // wave (64-lane) reduction
    #pragma unroll
    for (int off = 32; off > 0; off >>= 1) {
        s0 += __shfl_down(s0, off, 64);
        s1 += __shfl_down(s1, off, 64);
    }

    __shared__ float sm[(NTHREADS / 64) * 2];
    int wave = threadIdx.x >> 6;
    int lane = threadIdx.x & 63;
    if (lane == 0) { sm[wave * 2 + 0] = s0; sm[wave * 2 + 1] = s1; }
    __syncthreads();

    if (threadIdx.x == 0) {
        float b0 = 0.0f, b1 = 0.0f;
        #pragma unroll
        for (int wv = 0; wv < NTHREADS / 64; ++wv) {
            b0 += sm[wv * 2 + 0];
            b1 += sm[wv * 2 + 1];
        }
        partials[blockIdx.x] = make_float2(b0, b1);
    }
}

// Stage 2: one block reduces nblocks partial pairs -> 2 outputs.
__global__ __launch_bounds__(NTHREADS) void cl_final(
    const float2* __restrict__ partials,
    float* __restrict__ out,
    int nblocks,
    float invN)
{
    double s0 = 0.0, s1 = 0.0;
    for (int j = threadIdx.x; j < nblocks; j += NTHREADS) {
        float2 p = partials[j];
        s0 += (double)p.x;
        s1 += (double)p.y;
    }

    #pragma unroll
    for (int off = 32; off > 0; off >>= 1) {
        s0 += __shfl_down(s0, off, 64);
        s1 += __shfl_down(s1, off, 64);
    }

    __shared__ double dm[(NTHREADS / 64) * 2];
    int wave = threadIdx.x >> 6;
    int lane = threadIdx.x & 63;
    if (lane == 0) { dm[wave * 2 + 0] = s0; dm[wave * 2 + 1] = s1; }
    __syncthreads();

    if (threadIdx.x == 0) {
        double b0 = 0.0, b1 = 0.0;
        #pragma unroll
        for (int wv = 0; wv < NTHREADS / 64; ++wv) {
            b0 += dm[wv * 2 + 0];
            b1 += dm[wv * 2 + 1];
        }
        out[0] = (float)(-b0 * (double)invN);
        out[1] = (float)(-b1 * (double)invN);
    }
}

extern "C" void kernel_launch(void* const* d_in, const int* in_sizes, int n_in,
                              void* d_out, int out_size, void* d_ws, size_t ws_size,
                              hipStream_t stream) {
    const float* outputs = (const float*)d_in[0];  // (B,T,2)
    const float* targets = (const float*)d_in[1];  // (B,T,2)
    const float* weights = (const float*)d_in[2];  // (B,T)

    int N = in_sizes[2];        // B*T
    int M = N / 2;              // float4 groups

    float2* partials = (float2*)d_ws;
    float* out = (float*)d_out;

    int nblocks = (M + NTHREADS - 1) / NTHREADS;
    if (nblocks > NBLOCKS) nblocks = NBLOCKS;

    cl_partial<<<nblocks, NTHREADS, 0, stream>>>(
        (const float4*)outputs, (const float4*)targets, (const float2*)weights,
        partials, M);

    cl_final<<<1, NTHREADS, 0, stream>>>(partials, out, nblocks,
                                         1.0f / (float)N);
}